// Round 18
// baseline (2772.701 us; speedup 1.0000x reference)
//
#include <hip/hip_runtime.h>
#include <hip/hip_bf16.h>

#define NN      200000
#define D       64
#define NTILE   12500        // NN / 16
#define BKT_SH  8            // 256 rows per bucket
#define BKT_RW  256
#define NBKT    782          // ceil(NN / 256)
#define NCH     512          // scatter blocks (1024 threads); epb = 6250
#define EPB_CAP 6272         // LDS staging capacity (50 KB)
#define MAXRUN  512          // max runs per bucket = NCH
#define CPAD    16           // padded counters: one 64B line per bucket
#define ASTR    65           // accumulator row stride (floats): row % 32 bank spread

typedef __attribute__((ext_vector_type(8))) short short8;
typedef __attribute__((ext_vector_type(4))) short short4v;
typedef __attribute__((ext_vector_type(4))) float f32x4;

__device__ inline unsigned short f32_to_bf16_rne(float x) {
    unsigned u = __float_as_uint(x);
    unsigned r = u + 0x7FFFu + ((u >> 16) & 1u);
    return (unsigned short)(r >> 16);
}
__device__ inline float bf16_bits_to_f32(unsigned short h) {
    return __uint_as_float(((unsigned)h) << 16);
}
__device__ inline unsigned pack2_bf16_rne(float lo, float hi) {
    unsigned a = __float_as_uint(lo);
    unsigned b = __float_as_uint(hi);
    a = a + 0x7FFFu + ((a >> 16) & 1u);
    b = b + 0x7FFFu + ((b >> 16) & 1u);
    return (a >> 16) | (b & 0xFFFF0000u);
}
__device__ inline float bf_lo(unsigned u) { return __uint_as_float(u << 16); }
__device__ inline float bf_hi(unsigned u) { return __uint_as_float(u & 0xFFFF0000u); }

// ---------------- utility kernels ----------------
__global__ __launch_bounds__(256) void zero_f4(float4* __restrict__ p, int n4) {
    int i = blockIdx.x * blockDim.x + threadIdx.x;
    if (i < n4) p[i] = make_float4(0.f, 0.f, 0.f, 0.f);
}
__global__ __launch_bounds__(256) void zero_i(int* __restrict__ p, int n) {
    int i = blockIdx.x * blockDim.x + threadIdx.x;
    if (i < n) p[i] = 0;
}
__global__ __launch_bounds__(256) void cvt_bf16(const float2* __restrict__ in,
                                                unsigned* __restrict__ out, int n) {
    int stride = gridDim.x * blockDim.x;
    for (int i = blockIdx.x * blockDim.x + threadIdx.x; i < n; i += stride) {
        float2 v = in[i];
        out[i] = pack2_bf16_rne(v.x, v.y);
    }
}

// ---------------- single-pass scatter, LDS-staged: dense single-shot line writes ----------------
__global__ __launch_bounds__(1024) void scatter_v4(const int* __restrict__ rows,
                                                   const int* __restrict__ cols,
                                                   const float* __restrict__ vals,
                                                   int* __restrict__ gcur,
                                                   int* __restrict__ runcnt_p,
                                                   int2* __restrict__ runlist,
                                                   int2* __restrict__ packed1,
                                                   int E, int epb) {
    __shared__ int2 stage[EPB_CAP];   // 50 KB block-local packed region
    __shared__ int  h[NBKT];          // counts, then run cursors
    __shared__ int  off[NBKT];        // block-local exclusive offsets
    __shared__ int  s[1024];
    __shared__ int  gbase;
    int t = threadIdx.x;
    for (int i = t; i < NBKT; i += 1024) h[i] = 0;
    __syncthreads();
    int start = blockIdx.x * epb;
    int end   = min(E, start + epb);
    for (int e = start + t; e < end; e += 1024)
        atomicAdd(&h[rows[e] >> BKT_SH], 1);
    __syncthreads();
    int v = (t < NBKT) ? h[t] : 0;
    s[t] = v;
    __syncthreads();
    #pragma unroll
    for (int d = 1; d < 1024; d <<= 1) {
        int a = (t >= d) ? s[t - d] : 0;
        __syncthreads();
        s[t] += a;
        __syncthreads();
    }
    if (t < NBKT) off[t] = s[t] - v;
    if (t == 1023) gbase = atomicAdd(gcur, s[1023]);   // one reservation per block
    __syncthreads();
    int gb = gbase;
    for (int i = t; i < NBKT; i += 1024) {
        int c = h[i];
        if (c) {
            int idx = atomicAdd(&runcnt_p[i * CPAD], 1);
            runlist[(size_t)i * MAXRUN + idx] = make_int2(gb + off[i], c);
        }
        h[i] = 0;                                      // reuse as run cursor
    }
    __syncthreads();
    for (int e = start + t; e < end; e += 1024) {
        int r = rows[e];
        int b = r >> BKT_SH;
        int p = off[b] + atomicAdd(&h[b], 1);
        stage[p] = make_int2(cols[e] | ((r & (BKT_RW - 1)) << 18),
                             __float_as_int(vals[e]));
    }
    __syncthreads();
    int cnt = end - start;
    for (int i = t; i < cnt; i += 1024)
        packed1[gb + i] = stage[i];
}

// ---------------- bucket-block gather SpMM: LDS f32 accumulators, no sort ----------------
// One block per bucket (256 rows). Octet (8 lanes) per run; per edge: width-8 shfl
// broadcast of (c,v), uint4 gather of ein row slice, 8x ds_add_f32 into acc.
__global__ __launch_bounds__(1024) void spmm_bkt(const int* __restrict__ runcnt_p,
                                                 const int2* __restrict__ runlist,
                                                 const int2* __restrict__ packed1,
                                                 const uint4* __restrict__ ein,
                                                 uint4* __restrict__ out_bf) {
    __shared__ float acc[BKT_RW * ASTR];     // 256 x 65 f32 = 66.56 KB
    int b = blockIdx.x;
    int t = threadIdx.x;
    for (int i = t; i < BKT_RW * ASTR; i += 1024) acc[i] = 0.f;
    int rc = runcnt_p[b * CPAD];
    __syncthreads();

    int oct = t >> 3;          // 128 octets per block
    int l   = t & 7;
    const int2* rl_base = runlist + (size_t)b * MAXRUN;
    for (int run = oct; run < rc; run += 128) {
        int2 rl   = rl_base[run];
        int start = rl.x, len = rl.y;
        for (int j0 = 0; j0 < len; j0 += 8) {
            int jn = len - j0; if (jn > 8) jn = 8;
            int2 ev = make_int2(0, 0);
            if (l < jn) ev = packed1[start + j0 + l];
            for (int k = 0; k < jn; ++k) {
                int   cx = __shfl(ev.x, k, 8);
                float v  = __int_as_float(__shfl(ev.y, k, 8));
                int   c    = cx & 0x3FFFF;
                int   rloc = (cx >> 18) & 0xFF;
                uint4 g = ein[(size_t)c * 8 + l];
                float* a = &acc[rloc * ASTR + l * 8];
                atomicAdd(a + 0, v * bf_lo(g.x));
                atomicAdd(a + 1, v * bf_hi(g.x));
                atomicAdd(a + 2, v * bf_lo(g.y));
                atomicAdd(a + 3, v * bf_hi(g.y));
                atomicAdd(a + 4, v * bf_lo(g.z));
                atomicAdd(a + 5, v * bf_hi(g.z));
                atomicAdd(a + 6, v * bf_lo(g.w));
                atomicAdd(a + 7, v * bf_hi(g.w));
            }
        }
    }
    __syncthreads();

    int base_row = b << BKT_SH;
    for (int i = t; i < BKT_RW * 8; i += 1024) {   // 2048 uint4 per bucket
        int r = i >> 3, q = i & 7;
        int g = base_row + r;
        if (g < NN) {
            const float* a = &acc[r * ASTR + q * 8];
            out_bf[(size_t)g * 8 + q] =
                make_uint4(pack2_bf16_rne(a[0], a[1]), pack2_bf16_rne(a[2], a[3]),
                           pack2_bf16_rne(a[4], a[5]), pack2_bf16_rne(a[6], a[7]));
        }
    }
}

// ---------------- fallback scatter SpMM (atomic path) ----------------
__global__ __launch_bounds__(256) void spmm_scatter(const int* __restrict__ rows,
                                                    const int* __restrict__ cols,
                                                    const float* __restrict__ vals,
                                                    const float* __restrict__ ein,
                                                    float* __restrict__ eout, int E) {
    int gid  = blockIdx.x * blockDim.x + threadIdx.x;
    int wid  = gid >> 6;
    int lane = threadIdx.x & 63;
    int nw   = (gridDim.x * blockDim.x) >> 6;
    for (int e = wid; e < E; e += nw) {
        int   r = rows[e];
        int   c = cols[e];
        float v = vals[e];
        float x = ein[(size_t)c * D + lane];
        unsafeAtomicAdd(&eout[(size_t)r * D + lane], v * x);
    }
}

// ---------------- MFMA fused MLP+LN: W in LDS, coalesced LDS-staged tiles ----------------
template <int IN_BF16>
__global__ __launch_bounds__(256) void mlp_v2(const uint2* __restrict__ in_bf,
                                              float* __restrict__ out,
                                              const float* __restrict__ Ws,
                                              const float* __restrict__ bs,
                                              const float* __restrict__ gamma,
                                              const float* __restrict__ beta) {
    __shared__ unsigned short wlds[2][64][72];
    __shared__ float tb[4][16][68];

    int t    = threadIdx.x;
    int wv   = t >> 6;
    int lane = t & 63;
    int fr   = t & 15;
    int fq   = lane >> 4;

    for (int i = t * 4; i < 2 * 64 * 64; i += 1024) {
        float4 f = *(const float4*)(Ws + i);
        int l = i >> 12, r = (i >> 6) & 63, c = i & 63;
        short4v s4;
        s4[0] = (short)f32_to_bf16_rne(f.x);
        s4[1] = (short)f32_to_bf16_rne(f.y);
        s4[2] = (short)f32_to_bf16_rne(f.z);
        s4[3] = (short)f32_to_bf16_rne(f.w);
        *(short4v*)&wlds[l][r][c] = s4;
    }
    __syncthreads();

    float bia[2][4], gam[4], bet[4];
    #pragma unroll
    for (int nt = 0; nt < 4; ++nt) {
        bia[0][nt] = bs[nt * 16 + fr];
        bia[1][nt] = bs[64 + nt * 16 + fr];
        gam[nt]    = gamma[nt * 16 + fr];
        bet[nt]    = beta[nt * 16 + fr];
    }

    float (*tw)[68] = tb[wv];

    for (int tile = blockIdx.x * 4 + wv; tile < NTILE; tile += gridDim.x * 4) {
        float* baseo = out + (size_t)tile * 1024;

        if (IN_BF16) {
            const uint2* bi = in_bf + (size_t)tile * 256;
            #pragma unroll
            for (int it = 0; it < 4; ++it) {
                int idx = it * 64 + lane;
                uint2 u = bi[idx];
                int r = idx >> 4, c = (idx & 15) * 4;
                tw[r][c]     = bf_lo(u.x);
                tw[r][c + 1] = bf_hi(u.x);
                tw[r][c + 2] = bf_lo(u.y);
                tw[r][c + 3] = bf_hi(u.y);
            }
        } else {
            #pragma unroll
            for (int it = 0; it < 4; ++it) {
                int idx = it * 256 + lane * 4;
                *(float4*)&tw[idx >> 6][idx & 63] = *(const float4*)(baseo + idx);
            }
        }

        #pragma unroll
        for (int l = 0; l < 2; ++l) {
            short8 xh[2], xl[2];
            #pragma unroll
            for (int kk = 0; kk < 2; ++kk) {
                const float* s = &tw[fr][kk * 32 + fq * 8];
                float4 a = *(const float4*)s;
                float4 b4 = *(const float4*)(s + 4);
                float v[8] = {a.x, a.y, a.z, a.w, b4.x, b4.y, b4.z, b4.w};
                #pragma unroll
                for (int j = 0; j < 8; ++j) {
                    unsigned short hh = f32_to_bf16_rne(v[j]);
                    xh[kk][j] = (short)hh;
                    xl[kk][j] = (short)f32_to_bf16_rne(v[j] - bf16_bits_to_f32(hh));
                }
            }
            f32x4 acc[4];
            #pragma unroll
            for (int nt = 0; nt < 4; ++nt) {
                float bb = bia[l][nt];
                acc[nt] = f32x4{bb, bb, bb, bb};
                #pragma unroll
                for (int kk = 0; kk < 2; ++kk) {
                    short8 w8 = *(const short8*)&wlds[l][nt * 16 + fr][kk * 32 + fq * 8];
                    if (!(IN_BF16 && l == 0))
                        acc[nt] = __builtin_amdgcn_mfma_f32_16x16x32_bf16(xl[kk], w8, acc[nt], 0, 0, 0);
                    acc[nt] = __builtin_amdgcn_mfma_f32_16x16x32_bf16(xh[kk], w8, acc[nt], 0, 0, 0);
                }
            }
            #pragma unroll
            for (int nt = 0; nt < 4; ++nt)
                #pragma unroll
                for (int j = 0; j < 4; ++j) {
                    float* cell = &tw[fq * 4 + j][nt * 16 + fr];
                    *cell = fmaxf(acc[nt][j], 0.f) + *cell;
                }
        }

        float y2[4][4], sm[4], sq[4];
        #pragma unroll
        for (int j = 0; j < 4; ++j) { sm[j] = 0.f; sq[j] = 0.f; }
        #pragma unroll
        for (int nt = 0; nt < 4; ++nt)
            #pragma unroll
            for (int j = 0; j < 4; ++j) {
                float v = tw[fq * 4 + j][nt * 16 + fr];
                y2[nt][j] = v;
                sm[j] += v; sq[j] += v * v;
            }
        #pragma unroll
        for (int off = 1; off < 16; off <<= 1) {
            #pragma unroll
            for (int j = 0; j < 4; ++j) {
                sm[j] += __shfl_xor(sm[j], off);
                sq[j] += __shfl_xor(sq[j], off);
            }
        }
        #pragma unroll
        for (int j = 0; j < 4; ++j) {
            float mu  = sm[j] * (1.f / 64.f);
            float var = sq[j] * (1.f / 64.f) - mu * mu;
            float rs  = rsqrtf(var + 1e-5f);
            #pragma unroll
            for (int nt = 0; nt < 4; ++nt)
                tw[fq * 4 + j][nt * 16 + fr] = (y2[nt][j] - mu) * rs * gam[nt] + bet[nt];
        }

        #pragma unroll
        for (int it = 0; it < 4; ++it) {
            int idx = it * 256 + lane * 4;
            *(float4*)(baseo + idx) = *(const float4*)&tw[idx >> 6][idx & 63];
        }
    }
}

extern "C" void kernel_launch(void* const* d_in, const int* in_sizes, int n_in,
                              void* d_out, int out_size, void* d_ws, size_t ws_size,
                              hipStream_t stream) {
    const int*   rows  = (const int*)d_in[0];
    const int*   cols  = (const int*)d_in[1];
    const float* vals  = (const float*)d_in[2];
    const float* ini   = (const float*)d_in[3];
    const float* Ws    = (const float*)d_in[4];
    const float* bs    = (const float*)d_in[5];
    const float* gamma = (const float*)d_in[6];
    const float* beta  = (const float*)d_in[7];
    float* out = (float*)d_out;
    int E = in_sizes[0];

    size_t A_b   = (size_t)NN * 32 * 4;                           // ini_bf / hop-2 out
    size_t E_b   = A_b;                                           // e1_bf (hop-1 out)
    size_t P_b   = ((size_t)E * 8 + 63) & ~(size_t)63;            // packed1 (read by BOTH hops)
    size_t run_b = (size_t)NBKT * MAXRUN * 8;                     // 3.2 MB
    size_t rcp_b = ((size_t)NBKT * CPAD * 4 + 63) & ~(size_t)63;  // padded run counters
    size_t gc_b  = 64;
    size_t need  = A_b + E_b + P_b + run_b + rcp_b + gc_b;

    if (ws_size >= need && (size_t)E <= (size_t)NCH * EPB_CAP) {
        char* w = (char*)d_ws;
        unsigned* Abuf     = (unsigned*)w;  w += A_b;   // ini_bf -> hop-2 out -> mlp in
        unsigned* e1_bf    = (unsigned*)w;  w += E_b;
        int2*     packed1  = (int2*)w;      w += P_b;
        int2*     runlist  = (int2*)w;      w += run_b;
        int*      runcnt_p = (int*)w;       w += rcp_b;
        int*      gcur     = (int*)w;                   // zeroed with the counters

        int epb = (E + NCH - 1) / NCH;
        cvt_bf16<<<2048, 256, 0, stream>>>((const float2*)ini, Abuf, NN * 32);
        int zn = (int)((rcp_b + gc_b) / 4);
        zero_i<<<(zn + 255) / 256, 256, 0, stream>>>(runcnt_p, zn);
        scatter_v4<<<NCH, 1024, 0, stream>>>(rows, cols, vals, gcur, runcnt_p,
                                             runlist, packed1, E, epb);
        spmm_bkt<<<NBKT, 1024, 0, stream>>>(runcnt_p, runlist, packed1,
                                            (const uint4*)Abuf, (uint4*)e1_bf);
        spmm_bkt<<<NBKT, 1024, 0, stream>>>(runcnt_p, runlist, packed1,
                                            (const uint4*)e1_bf, (uint4*)Abuf);
        mlp_v2<1><<<1024, 256, 0, stream>>>((const uint2*)Abuf, out, Ws, bs, gamma, beta);
    } else {
        float* e1 = (float*)d_ws;
        int n4 = out_size / 4;
        int zb = (n4 + 255) / 256;
        zero_f4<<<zb, 256, 0, stream>>>((float4*)e1,  n4);
        zero_f4<<<zb, 256, 0, stream>>>((float4*)out, n4);
        spmm_scatter<<<12800, 256, 0, stream>>>(rows, cols, vals, ini, e1, E);
        spmm_scatter<<<12800, 256, 0, stream>>>(rows, cols, vals, e1, out, E);
        mlp_v2<0><<<1024, 256, 0, stream>>>(nullptr, out, Ws, bs, gamma, beta);
    }
}

// Round 19
// 232.636 us; speedup vs baseline: 11.9186x; 11.9186x over previous
//
#include <hip/hip_runtime.h>
#include <hip/hip_bf16.h>

#define NN      200000
#define D       64
#define NTILE   12500        // NN / 16
#define BKT_SH  8            // 256 rows per bucket
#define BKT_RW  256
#define NBKT    782          // ceil(NN / 256)
#define NCH     512          // scatter blocks (1024 threads); epb = 6250
#define EPB_CAP 6272         // LDS staging capacity (50 KB)
#define MAXRUN  512          // max runs per bucket = NCH
#define SCAP    4864         // sort LDS staging cap per bucket
#define CPAD    16           // padded counters: one 64B line per bucket

typedef __attribute__((ext_vector_type(8))) short short8;
typedef __attribute__((ext_vector_type(4))) short short4v;
typedef __attribute__((ext_vector_type(4))) float f32x4;

__device__ inline unsigned short f32_to_bf16_rne(float x) {
    unsigned u = __float_as_uint(x);
    unsigned r = u + 0x7FFFu + ((u >> 16) & 1u);
    return (unsigned short)(r >> 16);
}
__device__ inline float bf16_bits_to_f32(unsigned short h) {
    return __uint_as_float(((unsigned)h) << 16);
}
__device__ inline unsigned pack2_bf16_rne(float lo, float hi) {
    unsigned a = __float_as_uint(lo);
    unsigned b = __float_as_uint(hi);
    a = a + 0x7FFFu + ((a >> 16) & 1u);
    b = b + 0x7FFFu + ((b >> 16) & 1u);
    return (a >> 16) | (b & 0xFFFF0000u);
}
__device__ inline float bf_lo(unsigned u) { return __uint_as_float(u << 16); }
__device__ inline float bf_hi(unsigned u) { return __uint_as_float(u & 0xFFFF0000u); }

// ---------------- utility kernels ----------------
__global__ __launch_bounds__(256) void zero_f4(float4* __restrict__ p, int n4) {
    int i = blockIdx.x * blockDim.x + threadIdx.x;
    if (i < n4) p[i] = make_float4(0.f, 0.f, 0.f, 0.f);
}
__global__ __launch_bounds__(256) void zero_i(int* __restrict__ p, int n) {
    int i = blockIdx.x * blockDim.x + threadIdx.x;
    if (i < n) p[i] = 0;
}
__global__ __launch_bounds__(256) void cvt_bf16(const float2* __restrict__ in,
                                                unsigned* __restrict__ out, int n) {
    int stride = gridDim.x * blockDim.x;
    for (int i = blockIdx.x * blockDim.x + threadIdx.x; i < n; i += stride) {
        float2 v = in[i];
        out[i] = pack2_bf16_rne(v.x, v.y);
    }
}

// ---------------- single-pass scatter, LDS-staged: dense single-shot line writes ----------------
__global__ __launch_bounds__(1024) void scatter_v4(const int* __restrict__ rows,
                                                   const int* __restrict__ cols,
                                                   const float* __restrict__ vals,
                                                   int* __restrict__ gcur,
                                                   int* __restrict__ runcnt_p,
                                                   int2* __restrict__ runlist,
                                                   int* __restrict__ tot_p,
                                                   int2* __restrict__ packed1,
                                                   int E, int epb) {
    __shared__ int2 stage[EPB_CAP];   // 50 KB block-local packed region
    __shared__ int  h[NBKT];          // counts, then run cursors
    __shared__ int  off[NBKT];        // block-local exclusive offsets
    __shared__ int  s[1024];
    __shared__ int  gbase;
    int t = threadIdx.x;
    for (int i = t; i < NBKT; i += 1024) h[i] = 0;
    __syncthreads();
    int start = blockIdx.x * epb;
    int end   = min(E, start + epb);
    for (int e = start + t; e < end; e += 1024)
        atomicAdd(&h[rows[e] >> BKT_SH], 1);
    __syncthreads();
    int v = (t < NBKT) ? h[t] : 0;
    s[t] = v;
    __syncthreads();
    #pragma unroll
    for (int d = 1; d < 1024; d <<= 1) {
        int a = (t >= d) ? s[t - d] : 0;
        __syncthreads();
        s[t] += a;
        __syncthreads();
    }
    if (t < NBKT) off[t] = s[t] - v;
    if (t == 1023) gbase = atomicAdd(gcur, s[1023]);   // one reservation per block
    __syncthreads();
    int gb = gbase;
    for (int i = t; i < NBKT; i += 1024) {
        int c = h[i];
        if (c) {
            int idx = atomicAdd(&runcnt_p[i * CPAD], 1);
            runlist[(size_t)i * MAXRUN + idx] = make_int2(gb + off[i], c);
            atomicAdd(&tot_p[i * CPAD], c);
        }
        h[i] = 0;                                      // reuse as run cursor
    }
    __syncthreads();
    for (int e = start + t; e < end; e += 1024) {
        int r = rows[e];
        int b = r >> BKT_SH;
        int p = off[b] + atomicAdd(&h[b], 1);
        stage[p] = make_int2(cols[e] | ((r & (BKT_RW - 1)) << 18),
                             __float_as_int(vals[e]));
    }
    __syncthreads();
    int cnt = end - start;
    for (int i = t; i < cnt; i += 1024)
        packed1[gb + i] = stage[i];
}

// ---------------- scan bucket totals -> bktstart; rp[NN] = E ----------------
__global__ __launch_bounds__(1024) void bkt_scan3(const int* __restrict__ tot_p,
                                                  int* __restrict__ bktstart,
                                                  int* __restrict__ rp, int E) {
    __shared__ int s[1024];
    int t = threadIdx.x;
    int v = (t < NBKT) ? tot_p[t * CPAD] : 0;
    s[t] = v;
    __syncthreads();
    #pragma unroll
    for (int d = 1; d < 1024; d <<= 1) {
        int a = (t >= d) ? s[t - d] : 0;
        __syncthreads();
        s[t] += a;
        __syncthreads();
    }
    if (t < NBKT) bktstart[t] = s[t] - v;
    if (t == 0) { bktstart[NBKT] = E; rp[NN] = E; }
}

// ---------------- per-bucket sort via run list -> dense exact CSR ----------------
// Load phase: run-parallel copy (octet per run) -- no per-element binary search.
__global__ __launch_bounds__(512) void sort_v3(const int* __restrict__ bktstart,
                                               const int* __restrict__ runcnt_p,
                                               const int2* __restrict__ runlist,
                                               const int2* __restrict__ packed1,
                                               int2* __restrict__ packed2,
                                               int* __restrict__ rp) {
    __shared__ int2 sm[SCAP];
    __shared__ int  runoff[MAXRUN];
    __shared__ int  rstart[MAXRUN];
    __shared__ int  rlen[MAXRUN];
    __shared__ int  s2[512];
    __shared__ int  cnt[BKT_RW];
    __shared__ int  cur[BKT_RW];
    int b = blockIdx.x;
    int t = threadIdx.x;
    int rc = runcnt_p[b * CPAD];

    int len = 0, st = 0;
    if (t < rc) { int2 rl = runlist[(size_t)b * MAXRUN + t]; st = rl.x; len = rl.y; }
    rstart[t] = st;
    rlen[t]   = len;
    s2[t] = len;
    __syncthreads();
    #pragma unroll
    for (int d = 1; d < 512; d <<= 1) {
        int a = (t >= d) ? s2[t - d] : 0;
        __syncthreads();
        s2[t] += a;
        __syncthreads();
    }
    runoff[t] = s2[t] - len;          // exclusive prefix of run lengths
    if (t < BKT_RW) cnt[t] = 0;
    __syncthreads();

    // run-parallel load: octet (8 lanes) per run, stride 64 octets
    int oct = t >> 3;
    int l   = t & 7;
    for (int run = oct; run < rc; run += 64) {
        int rs = rstart[run];
        int ro = runoff[run];
        int rl = rlen[run];
        for (int j = l; j < rl; j += 8) {
            int dst = ro + j;
            if (dst < SCAP) {
                int2 v = packed1[rs + j];
                sm[dst] = v;
                atomicAdd(&cnt[(v.x >> 18) & (BKT_RW - 1)], 1);
            }
        }
    }
    __syncthreads();
    int n = s2[511]; if (n > SCAP) n = SCAP;
    #pragma unroll
    for (int d = 1; d < BKT_RW; d <<= 1) {
        int a = (t >= d && t < BKT_RW) ? cnt[t - d] : 0;
        __syncthreads();
        if (t < BKT_RW) cnt[t] += a;
        __syncthreads();
    }
    int sgl = bktstart[b];
    if (t < BKT_RW) {
        int ex = t ? cnt[t - 1] : 0;
        cur[t] = ex;
        int g = (b << BKT_SH) + t;
        if (g < NN) rp[g] = sgl + ex;
    }
    __syncthreads();
    for (int i = t; i < n; i += 512) {
        int2 v = sm[i];
        int  p = atomicAdd(&cur[(v.x >> 18) & (BKT_RW - 1)], 1);
        packed2[sgl + p] = make_int2(v.x & 0x3FFFF, v.y);
    }
}

// ---------------- gather SpMM, 4 rows/wave, quarter-wave per row, bf16 out ----------------
__global__ __launch_bounds__(256) void spmm_g(const int* __restrict__ rp,
                                              const int* __restrict__ rpe,
                                              const int2* __restrict__ packed,
                                              const uint2* __restrict__ ein,
                                              uint2* __restrict__ out_bf, int n) {
    int wave = (blockIdx.x * 256 + threadIdx.x) >> 6;
    int lane = threadIdx.x & 63;
    int l    = lane & 15;
    int row  = wave * 4 + (lane >> 4);
    if (row >= n) return;

    float ax = 0.f, ay = 0.f, az = 0.f, aw = 0.f;
    int s = rp[row], e = rpe[row];
    for (int base = s; base < e; base += 16) {
        int cnt = e - base; if (cnt > 16) cnt = 16;
        int2 ev = make_int2(0, 0);
        if (l < cnt) ev = packed[base + l];
        int k = 0;
        for (; k + 4 <= cnt; k += 4) {
            int   c0 = __shfl(ev.x, k,     16), c1 = __shfl(ev.x, k + 1, 16);
            int   c2 = __shfl(ev.x, k + 2, 16), c3 = __shfl(ev.x, k + 3, 16);
            float v0 = __int_as_float(__shfl(ev.y, k,     16));
            float v1 = __int_as_float(__shfl(ev.y, k + 1, 16));
            float v2 = __int_as_float(__shfl(ev.y, k + 2, 16));
            float v3 = __int_as_float(__shfl(ev.y, k + 3, 16));
            uint2 g0 = ein[c0 * 16 + l];
            uint2 g1 = ein[c1 * 16 + l];
            uint2 g2 = ein[c2 * 16 + l];
            uint2 g3 = ein[c3 * 16 + l];
            ax += v0 * bf_lo(g0.x); ay += v0 * bf_hi(g0.x);
            az += v0 * bf_lo(g0.y); aw += v0 * bf_hi(g0.y);
            ax += v1 * bf_lo(g1.x); ay += v1 * bf_hi(g1.x);
            az += v1 * bf_lo(g1.y); aw += v1 * bf_hi(g1.y);
            ax += v2 * bf_lo(g2.x); ay += v2 * bf_hi(g2.x);
            az += v2 * bf_lo(g2.y); aw += v2 * bf_hi(g2.y);
            ax += v3 * bf_lo(g3.x); ay += v3 * bf_hi(g3.x);
            az += v3 * bf_lo(g3.y); aw += v3 * bf_hi(g3.y);
        }
        for (; k < cnt; ++k) {
            int   c0 = __shfl(ev.x, k, 16);
            float v0 = __int_as_float(__shfl(ev.y, k, 16));
            uint2 g0 = ein[c0 * 16 + l];
            ax += v0 * bf_lo(g0.x); ay += v0 * bf_hi(g0.x);
            az += v0 * bf_lo(g0.y); aw += v0 * bf_hi(g0.y);
        }
    }
    out_bf[(size_t)row * 16 + l] = make_uint2(pack2_bf16_rne(ax, ay), pack2_bf16_rne(az, aw));
}

// ---------------- fallback scatter SpMM (atomic path) ----------------
__global__ __launch_bounds__(256) void spmm_scatter(const int* __restrict__ rows,
                                                    const int* __restrict__ cols,
                                                    const float* __restrict__ vals,
                                                    const float* __restrict__ ein,
                                                    float* __restrict__ eout, int E) {
    int gid  = blockIdx.x * blockDim.x + threadIdx.x;
    int wid  = gid >> 6;
    int lane = threadIdx.x & 63;
    int nw   = (gridDim.x * blockDim.x) >> 6;
    for (int e = wid; e < E; e += nw) {
        int   r = rows[e];
        int   c = cols[e];
        float v = vals[e];
        float x = ein[(size_t)c * D + lane];
        unsafeAtomicAdd(&eout[(size_t)r * D + lane], v * x);
    }
}

// ---------------- MFMA fused MLP+LN: W in LDS, coalesced LDS-staged tiles ----------------
template <int IN_BF16>
__global__ __launch_bounds__(256) void mlp_v2(const uint2* __restrict__ in_bf,
                                              float* __restrict__ out,
                                              const float* __restrict__ Ws,
                                              const float* __restrict__ bs,
                                              const float* __restrict__ gamma,
                                              const float* __restrict__ beta) {
    __shared__ unsigned short wlds[2][64][72];
    __shared__ float tb[4][16][68];

    int t    = threadIdx.x;
    int wv   = t >> 6;
    int lane = t & 63;
    int fr   = t & 15;
    int fq   = lane >> 4;

    for (int i = t * 4; i < 2 * 64 * 64; i += 1024) {
        float4 f = *(const float4*)(Ws + i);
        int l = i >> 12, r = (i >> 6) & 63, c = i & 63;
        short4v s4;
        s4[0] = (short)f32_to_bf16_rne(f.x);
        s4[1] = (short)f32_to_bf16_rne(f.y);
        s4[2] = (short)f32_to_bf16_rne(f.z);
        s4[3] = (short)f32_to_bf16_rne(f.w);
        *(short4v*)&wlds[l][r][c] = s4;
    }
    __syncthreads();

    float bia[2][4], gam[4], bet[4];
    #pragma unroll
    for (int nt = 0; nt < 4; ++nt) {
        bia[0][nt] = bs[nt * 16 + fr];
        bia[1][nt] = bs[64 + nt * 16 + fr];
        gam[nt]    = gamma[nt * 16 + fr];
        bet[nt]    = beta[nt * 16 + fr];
    }

    float (*tw)[68] = tb[wv];

    for (int tile = blockIdx.x * 4 + wv; tile < NTILE; tile += gridDim.x * 4) {
        float* baseo = out + (size_t)tile * 1024;

        if (IN_BF16) {
            const uint2* bi = in_bf + (size_t)tile * 256;
            #pragma unroll
            for (int it = 0; it < 4; ++it) {
                int idx = it * 64 + lane;
                uint2 u = bi[idx];
                int r = idx >> 4, c = (idx & 15) * 4;
                tw[r][c]     = bf_lo(u.x);
                tw[r][c + 1] = bf_hi(u.x);
                tw[r][c + 2] = bf_lo(u.y);
                tw[r][c + 3] = bf_hi(u.y);
            }
        } else {
            #pragma unroll
            for (int it = 0; it < 4; ++it) {
                int idx = it * 256 + lane * 4;
                *(float4*)&tw[idx >> 6][idx & 63] = *(const float4*)(baseo + idx);
            }
        }

        #pragma unroll
        for (int l = 0; l < 2; ++l) {
            short8 xh[2], xl[2];
            #pragma unroll
            for (int kk = 0; kk < 2; ++kk) {
                const float* s = &tw[fr][kk * 32 + fq * 8];
                float4 a = *(const float4*)s;
                float4 b4 = *(const float4*)(s + 4);
                float v[8] = {a.x, a.y, a.z, a.w, b4.x, b4.y, b4.z, b4.w};
                #pragma unroll
                for (int j = 0; j < 8; ++j) {
                    unsigned short hh = f32_to_bf16_rne(v[j]);
                    xh[kk][j] = (short)hh;
                    xl[kk][j] = (short)f32_to_bf16_rne(v[j] - bf16_bits_to_f32(hh));
                }
            }
            f32x4 acc[4];
            #pragma unroll
            for (int nt = 0; nt < 4; ++nt) {
                float bb = bia[l][nt];
                acc[nt] = f32x4{bb, bb, bb, bb};
                #pragma unroll
                for (int kk = 0; kk < 2; ++kk) {
                    short8 w8 = *(const short8*)&wlds[l][nt * 16 + fr][kk * 32 + fq * 8];
                    if (!(IN_BF16 && l == 0))
                        acc[nt] = __builtin_amdgcn_mfma_f32_16x16x32_bf16(xl[kk], w8, acc[nt], 0, 0, 0);
                    acc[nt] = __builtin_amdgcn_mfma_f32_16x16x32_bf16(xh[kk], w8, acc[nt], 0, 0, 0);
                }
            }
            #pragma unroll
            for (int nt = 0; nt < 4; ++nt)
                #pragma unroll
                for (int j = 0; j < 4; ++j) {
                    float* cell = &tw[fq * 4 + j][nt * 16 + fr];
                    *cell = fmaxf(acc[nt][j], 0.f) + *cell;
                }
        }

        float y2[4][4], sm[4], sq[4];
        #pragma unroll
        for (int j = 0; j < 4; ++j) { sm[j] = 0.f; sq[j] = 0.f; }
        #pragma unroll
        for (int nt = 0; nt < 4; ++nt)
            #pragma unroll
            for (int j = 0; j < 4; ++j) {
                float v = tw[fq * 4 + j][nt * 16 + fr];
                y2[nt][j] = v;
                sm[j] += v; sq[j] += v * v;
            }
        #pragma unroll
        for (int off = 1; off < 16; off <<= 1) {
            #pragma unroll
            for (int j = 0; j < 4; ++j) {
                sm[j] += __shfl_xor(sm[j], off);
                sq[j] += __shfl_xor(sq[j], off);
            }
        }
        #pragma unroll
        for (int j = 0; j < 4; ++j) {
            float mu  = sm[j] * (1.f / 64.f);
            float var = sq[j] * (1.f / 64.f) - mu * mu;
            float rs  = rsqrtf(var + 1e-5f);
            #pragma unroll
            for (int nt = 0; nt < 4; ++nt)
                tw[fq * 4 + j][nt * 16 + fr] = (y2[nt][j] - mu) * rs * gam[nt] + bet[nt];
        }

        #pragma unroll
        for (int it = 0; it < 4; ++it) {
            int idx = it * 256 + lane * 4;
            *(float4*)(baseo + idx) = *(const float4*)&tw[idx >> 6][idx & 63];
        }
    }
}

extern "C" void kernel_launch(void* const* d_in, const int* in_sizes, int n_in,
                              void* d_out, int out_size, void* d_ws, size_t ws_size,
                              hipStream_t stream) {
    const int*   rows  = (const int*)d_in[0];
    const int*   cols  = (const int*)d_in[1];
    const float* vals  = (const float*)d_in[2];
    const float* ini   = (const float*)d_in[3];
    const float* Ws    = (const float*)d_in[4];
    const float* bs    = (const float*)d_in[5];
    const float* gamma = (const float*)d_in[6];
    const float* beta  = (const float*)d_in[7];
    float* out = (float*)d_out;
    int E = in_sizes[0];

    size_t A_b   = (size_t)NN * 32 * 4;                           // bf16 rows buffer
    size_t e8    = (size_t)E * 8;
    size_t B_b   = (A_b > e8) ? A_b : e8;                         // packed1 / e1_bf union
    size_t C_b   = e8;                                            // packed2
    size_t run_b = (size_t)NBKT * MAXRUN * 8;
    size_t rcp_b = ((size_t)NBKT * CPAD * 4 + 63) & ~(size_t)63;
    size_t gc_b  = 64;
    size_t rp_b  = (((size_t)NN + 1) * 4 + 63) & ~(size_t)63;
    size_t bst_b = (((size_t)NBKT + 1) * 4 + 63) & ~(size_t)63;
    size_t need  = A_b + B_b + C_b + run_b + 2 * rcp_b + gc_b + rp_b + bst_b;

    if (ws_size >= need && (size_t)E <= (size_t)NCH * EPB_CAP) {
        char* w = (char*)d_ws;
        unsigned* Abuf     = (unsigned*)w;  w += A_b;   // ini_bf -> hop2 out -> mlp in
        char*     Bbuf     = w;             w += B_b;   // packed1, then e1_bf
        int2*     packed2  = (int2*)w;      w += C_b;
        int2*     runlist  = (int2*)w;      w += run_b;
        int*      runcnt_p = (int*)w;       w += rcp_b;
        int*      tot_p    = (int*)w;       w += rcp_b;
        int*      gcur     = (int*)w;       w += gc_b;  // zeroed with the counters
        int*      rp       = (int*)w;       w += rp_b;
        int*      bktstart = (int*)w;

        int2*     packed1  = (int2*)Bbuf;
        unsigned* e1_bf    = (unsigned*)Bbuf;

        int epb = (E + NCH - 1) / NCH;
        cvt_bf16<<<2048, 256, 0, stream>>>((const float2*)ini, Abuf, NN * 32);
        int zn = (int)((2 * rcp_b + gc_b) / 4);
        zero_i<<<(zn + 255) / 256, 256, 0, stream>>>(runcnt_p, zn);
        scatter_v4<<<NCH, 1024, 0, stream>>>(rows, cols, vals, gcur, runcnt_p,
                                             runlist, tot_p, packed1, E, epb);
        bkt_scan3<<<1, 1024, 0, stream>>>(tot_p, bktstart, rp, E);
        sort_v3<<<NBKT, 512, 0, stream>>>(bktstart, runcnt_p, runlist,
                                          packed1, packed2, rp);
        spmm_g<<<NTILE, 256, 0, stream>>>(rp, rp + 1, packed2, (const uint2*)Abuf,
                                          (uint2*)e1_bf, NN);
        spmm_g<<<NTILE, 256, 0, stream>>>(rp, rp + 1, packed2, (const uint2*)e1_bf,
                                          (uint2*)Abuf, NN);
        mlp_v2<1><<<1024, 256, 0, stream>>>((const uint2*)Abuf, out, Ws, bs, gamma, beta);
    } else {
        float* e1 = (float*)d_ws;
        int n4 = out_size / 4;
        int zb = (n4 + 255) / 256;
        zero_f4<<<zb, 256, 0, stream>>>((float4*)e1,  n4);
        zero_f4<<<zb, 256, 0, stream>>>((float4*)out, n4);
        spmm_scatter<<<12800, 256, 0, stream>>>(rows, cols, vals, ini, e1, E);
        spmm_scatter<<<12800, 256, 0, stream>>>(rows, cols, vals, e1, out, E);
        mlp_v2<0><<<1024, 256, 0, stream>>>(nullptr, out, Ws, bs, gamma, beta);
    }
}

// Round 20
// 227.760 us; speedup vs baseline: 12.1738x; 1.0214x over previous
//
#include <hip/hip_runtime.h>
#include <hip/hip_bf16.h>

#define NN      200000
#define D       64
#define NTILE   12500        // NN / 16
#define BKT_SH  8            // 256 rows per bucket
#define BKT_RW  256
#define NBKT    782          // ceil(NN / 256)
#define NCH     512          // scatter blocks (1024 threads); epb = 6250
#define EPB_CAP 6272         // LDS staging capacity (50 KB)
#define MAXRUN  512          // max runs per bucket = NCH
#define SCAP    4864         // sort LDS staging cap per bucket
#define CPAD    16           // padded counters: one 64B line per bucket
#define RITER   8            // max per-thread edges in scatter (ceil(6250/1024)+1)

typedef __attribute__((ext_vector_type(8))) short short8;
typedef __attribute__((ext_vector_type(4))) short short4v;
typedef __attribute__((ext_vector_type(4))) float f32x4;

__device__ inline unsigned short f32_to_bf16_rne(float x) {
    unsigned u = __float_as_uint(x);
    unsigned r = u + 0x7FFFu + ((u >> 16) & 1u);
    return (unsigned short)(r >> 16);
}
__device__ inline float bf16_bits_to_f32(unsigned short h) {
    return __uint_as_float(((unsigned)h) << 16);
}
__device__ inline unsigned pack2_bf16_rne(float lo, float hi) {
    unsigned a = __float_as_uint(lo);
    unsigned b = __float_as_uint(hi);
    a = a + 0x7FFFu + ((a >> 16) & 1u);
    b = b + 0x7FFFu + ((b >> 16) & 1u);
    return (a >> 16) | (b & 0xFFFF0000u);
}
__device__ inline float bf_lo(unsigned u) { return __uint_as_float(u << 16); }
__device__ inline float bf_hi(unsigned u) { return __uint_as_float(u & 0xFFFF0000u); }

// ---------------- utility kernels ----------------
__global__ __launch_bounds__(256) void zero_f4(float4* __restrict__ p, int n4) {
    int i = blockIdx.x * blockDim.x + threadIdx.x;
    if (i < n4) p[i] = make_float4(0.f, 0.f, 0.f, 0.f);
}
__global__ __launch_bounds__(256) void zero_i(int* __restrict__ p, int n) {
    int i = blockIdx.x * blockDim.x + threadIdx.x;
    if (i < n) p[i] = 0;
}
__global__ __launch_bounds__(256) void cvt_bf16(const float2* __restrict__ in,
                                                unsigned* __restrict__ out, int n) {
    int stride = gridDim.x * blockDim.x;
    for (int i = blockIdx.x * blockDim.x + threadIdx.x; i < n; i += stride) {
        float2 v = in[i];
        out[i] = pack2_bf16_rne(v.x, v.y);
    }
}

// ---------------- single-pass scatter, LDS-staged; rows cached in registers ----------------
__global__ __launch_bounds__(1024) void scatter_v4(const int* __restrict__ rows,
                                                   const int* __restrict__ cols,
                                                   const float* __restrict__ vals,
                                                   int* __restrict__ gcur,
                                                   int* __restrict__ runcnt_p,
                                                   int2* __restrict__ runlist,
                                                   int* __restrict__ tot_p,
                                                   int2* __restrict__ packed1,
                                                   int E, int epb) {
    __shared__ int2 stage[EPB_CAP];   // 50 KB block-local packed region
    __shared__ int  h[NBKT];          // counts, then run cursors
    __shared__ int  off[NBKT];        // block-local exclusive offsets
    __shared__ int  s[1024];
    __shared__ int  gbase;
    int t = threadIdx.x;
    for (int i = t; i < NBKT; i += 1024) h[i] = 0;
    __syncthreads();
    int start = blockIdx.x * epb;
    int end   = min(E, start + epb);

    int rcache[RITER];
    #pragma unroll
    for (int it = 0; it < RITER; ++it) {
        int e = start + it * 1024 + t;
        int r = -1;
        if (e < end) { r = rows[e]; atomicAdd(&h[r >> BKT_SH], 1); }
        rcache[it] = r;
    }
    __syncthreads();
    int v = (t < NBKT) ? h[t] : 0;
    s[t] = v;
    __syncthreads();
    #pragma unroll
    for (int d = 1; d < 1024; d <<= 1) {
        int a = (t >= d) ? s[t - d] : 0;
        __syncthreads();
        s[t] += a;
        __syncthreads();
    }
    if (t < NBKT) off[t] = s[t] - v;
    if (t == 1023) gbase = atomicAdd(gcur, s[1023]);   // one reservation per block
    __syncthreads();
    int gb = gbase;
    for (int i = t; i < NBKT; i += 1024) {
        int c = h[i];
        if (c) {
            int idx = atomicAdd(&runcnt_p[i * CPAD], 1);
            runlist[(size_t)i * MAXRUN + idx] = make_int2(gb + off[i], c);
            atomicAdd(&tot_p[i * CPAD], c);
        }
        h[i] = 0;                                      // reuse as run cursor
    }
    __syncthreads();
    #pragma unroll
    for (int it = 0; it < RITER; ++it) {
        int r = rcache[it];
        if (r >= 0) {
            int e = start + it * 1024 + t;
            int b = r >> BKT_SH;
            int p = off[b] + atomicAdd(&h[b], 1);
            stage[p] = make_int2(cols[e] | ((r & (BKT_RW - 1)) << 18),
                                 __float_as_int(vals[e]));
        }
    }
    __syncthreads();
    int cnt = end - start;
    for (int i = t; i < cnt; i += 1024)
        packed1[gb + i] = stage[i];
}

// ---------------- scan bucket totals -> bktstart; rp[NN] = E ----------------
__global__ __launch_bounds__(1024) void bkt_scan3(const int* __restrict__ tot_p,
                                                  int* __restrict__ bktstart,
                                                  int* __restrict__ rp, int E) {
    __shared__ int s[1024];
    int t = threadIdx.x;
    int v = (t < NBKT) ? tot_p[t * CPAD] : 0;
    s[t] = v;
    __syncthreads();
    #pragma unroll
    for (int d = 1; d < 1024; d <<= 1) {
        int a = (t >= d) ? s[t - d] : 0;
        __syncthreads();
        s[t] += a;
        __syncthreads();
    }
    if (t < NBKT) bktstart[t] = s[t] - v;
    if (t == 0) { bktstart[NBKT] = E; rp[NN] = E; }
}

// ---------------- per-bucket sort via run list -> dense exact CSR (1024 threads) ----------------
__global__ __launch_bounds__(1024) void sort_v3(const int* __restrict__ bktstart,
                                                const int* __restrict__ runcnt_p,
                                                const int2* __restrict__ runlist,
                                                const int2* __restrict__ packed1,
                                                int2* __restrict__ packed2,
                                                int* __restrict__ rp) {
    __shared__ int2 sm[SCAP];
    __shared__ int  runoff[MAXRUN];
    __shared__ int  rstart[MAXRUN];
    __shared__ int  rlen[MAXRUN];
    __shared__ int  s2[1024];
    __shared__ int  cnt[BKT_RW];
    __shared__ int  cur[BKT_RW];
    int b = blockIdx.x;
    int t = threadIdx.x;
    int rc = runcnt_p[b * CPAD];

    int len = 0, st = 0;
    if (t < rc) { int2 rl = runlist[(size_t)b * MAXRUN + t]; st = rl.x; len = rl.y; }
    if (t < MAXRUN) { rstart[t] = st; rlen[t] = len; }
    s2[t] = len;                        // t >= rc (incl. t >= MAXRUN) contribute 0
    __syncthreads();
    #pragma unroll
    for (int d = 1; d < 1024; d <<= 1) {
        int a = (t >= d) ? s2[t - d] : 0;
        __syncthreads();
        s2[t] += a;
        __syncthreads();
    }
    if (t < MAXRUN) runoff[t] = s2[t] - len;
    if (t < BKT_RW) cnt[t] = 0;
    __syncthreads();

    // run-parallel load: octet (8 lanes) per run, 128 octets
    int oct = t >> 3;
    int l   = t & 7;
    for (int run = oct; run < rc; run += 128) {
        int rs = rstart[run];
        int ro = runoff[run];
        int rl = rlen[run];
        for (int j = l; j < rl; j += 8) {
            int dst = ro + j;
            if (dst < SCAP) {
                int2 v = packed1[rs + j];
                sm[dst] = v;
                atomicAdd(&cnt[(v.x >> 18) & (BKT_RW - 1)], 1);
            }
        }
    }
    __syncthreads();
    int n = s2[1023]; if (n > SCAP) n = SCAP;
    #pragma unroll
    for (int d = 1; d < BKT_RW; d <<= 1) {
        int a = (t >= d && t < BKT_RW) ? cnt[t - d] : 0;
        __syncthreads();
        if (t < BKT_RW) cnt[t] += a;
        __syncthreads();
    }
    int sgl = bktstart[b];
    if (t < BKT_RW) {
        int ex = t ? cnt[t - 1] : 0;
        cur[t] = ex;
        int g = (b << BKT_SH) + t;
        if (g < NN) rp[g] = sgl + ex;
    }
    __syncthreads();
    for (int i = t; i < n; i += 1024) {
        int2 v = sm[i];
        int  p = atomicAdd(&cur[(v.x >> 18) & (BKT_RW - 1)], 1);
        packed2[sgl + p] = make_int2(v.x & 0x3FFFF, v.y);
    }
}

// ---------------- gather SpMM, 4 rows/wave, quarter-wave per row, bf16 out ----------------
__global__ __launch_bounds__(256) void spmm_g(const int* __restrict__ rp,
                                              const int* __restrict__ rpe,
                                              const int2* __restrict__ packed,
                                              const uint2* __restrict__ ein,
                                              uint2* __restrict__ out_bf, int n) {
    int wave = (blockIdx.x * 256 + threadIdx.x) >> 6;
    int lane = threadIdx.x & 63;
    int l    = lane & 15;
    int row  = wave * 4 + (lane >> 4);
    if (row >= n) return;

    float ax = 0.f, ay = 0.f, az = 0.f, aw = 0.f;
    int s = rp[row], e = rpe[row];
    for (int base = s; base < e; base += 16) {
        int cnt = e - base; if (cnt > 16) cnt = 16;
        int2 ev = make_int2(0, 0);
        if (l < cnt) ev = packed[base + l];
        int k = 0;
        for (; k + 4 <= cnt; k += 4) {
            int   c0 = __shfl(ev.x, k,     16), c1 = __shfl(ev.x, k + 1, 16);
            int   c2 = __shfl(ev.x, k + 2, 16), c3 = __shfl(ev.x, k + 3, 16);
            float v0 = __int_as_float(__shfl(ev.y, k,     16));
            float v1 = __int_as_float(__shfl(ev.y, k + 1, 16));
            float v2 = __int_as_float(__shfl(ev.y, k + 2, 16));
            float v3 = __int_as_float(__shfl(ev.y, k + 3, 16));
            uint2 g0 = ein[c0 * 16 + l];
            uint2 g1 = ein[c1 * 16 + l];
            uint2 g2 = ein[c2 * 16 + l];
            uint2 g3 = ein[c3 * 16 + l];
            ax += v0 * bf_lo(g0.x); ay += v0 * bf_hi(g0.x);
            az += v0 * bf_lo(g0.y); aw += v0 * bf_hi(g0.y);
            ax += v1 * bf_lo(g1.x); ay += v1 * bf_hi(g1.x);
            az += v1 * bf_lo(g1.y); aw += v1 * bf_hi(g1.y);
            ax += v2 * bf_lo(g2.x); ay += v2 * bf_hi(g2.x);
            az += v2 * bf_lo(g2.y); aw += v2 * bf_hi(g2.y);
            ax += v3 * bf_lo(g3.x); ay += v3 * bf_hi(g3.x);
            az += v3 * bf_lo(g3.y); aw += v3 * bf_hi(g3.y);
        }
        for (; k < cnt; ++k) {
            int   c0 = __shfl(ev.x, k, 16);
            float v0 = __int_as_float(__shfl(ev.y, k, 16));
            uint2 g0 = ein[c0 * 16 + l];
            ax += v0 * bf_lo(g0.x); ay += v0 * bf_hi(g0.x);
            az += v0 * bf_lo(g0.y); aw += v0 * bf_hi(g0.y);
        }
    }
    out_bf[(size_t)row * 16 + l] = make_uint2(pack2_bf16_rne(ax, ay), pack2_bf16_rne(az, aw));
}

// ---------------- fallback scatter SpMM (atomic path) ----------------
__global__ __launch_bounds__(256) void spmm_scatter(const int* __restrict__ rows,
                                                    const int* __restrict__ cols,
                                                    const float* __restrict__ vals,
                                                    const float* __restrict__ ein,
                                                    float* __restrict__ eout, int E) {
    int gid  = blockIdx.x * blockDim.x + threadIdx.x;
    int wid  = gid >> 6;
    int lane = threadIdx.x & 63;
    int nw   = (gridDim.x * blockDim.x) >> 6;
    for (int e = wid; e < E; e += nw) {
        int   r = rows[e];
        int   c = cols[e];
        float v = vals[e];
        float x = ein[(size_t)c * D + lane];
        unsafeAtomicAdd(&eout[(size_t)r * D + lane], v * x);
    }
}

// ---------------- MFMA fused MLP+LN: W in LDS, coalesced LDS-staged tiles ----------------
template <int IN_BF16>
__global__ __launch_bounds__(256) void mlp_v2(const uint2* __restrict__ in_bf,
                                              float* __restrict__ out,
                                              const float* __restrict__ Ws,
                                              const float* __restrict__ bs,
                                              const float* __restrict__ gamma,
                                              const float* __restrict__ beta) {
    __shared__ unsigned short wlds[2][64][72];
    __shared__ float tb[4][16][68];

    int t    = threadIdx.x;
    int wv   = t >> 6;
    int lane = t & 63;
    int fr   = t & 15;
    int fq   = lane >> 4;

    for (int i = t * 4; i < 2 * 64 * 64; i += 1024) {
        float4 f = *(const float4*)(Ws + i);
        int l = i >> 12, r = (i >> 6) & 63, c = i & 63;
        short4v s4;
        s4[0] = (short)f32_to_bf16_rne(f.x);
        s4[1] = (short)f32_to_bf16_rne(f.y);
        s4[2] = (short)f32_to_bf16_rne(f.z);
        s4[3] = (short)f32_to_bf16_rne(f.w);
        *(short4v*)&wlds[l][r][c] = s4;
    }
    __syncthreads();

    float bia[2][4], gam[4], bet[4];
    #pragma unroll
    for (int nt = 0; nt < 4; ++nt) {
        bia[0][nt] = bs[nt * 16 + fr];
        bia[1][nt] = bs[64 + nt * 16 + fr];
        gam[nt]    = gamma[nt * 16 + fr];
        bet[nt]    = beta[nt * 16 + fr];
    }

    float (*tw)[68] = tb[wv];

    for (int tile = blockIdx.x * 4 + wv; tile < NTILE; tile += gridDim.x * 4) {
        float* baseo = out + (size_t)tile * 1024;

        if (IN_BF16) {
            const uint2* bi = in_bf + (size_t)tile * 256;
            #pragma unroll
            for (int it = 0; it < 4; ++it) {
                int idx = it * 64 + lane;
                uint2 u = bi[idx];
                int r = idx >> 4, c = (idx & 15) * 4;
                tw[r][c]     = bf_lo(u.x);
                tw[r][c + 1] = bf_hi(u.x);
                tw[r][c + 2] = bf_lo(u.y);
                tw[r][c + 3] = bf_hi(u.y);
            }
        } else {
            #pragma unroll
            for (int it = 0; it < 4; ++it) {
                int idx = it * 256 + lane * 4;
                *(float4*)&tw[idx >> 6][idx & 63] = *(const float4*)(baseo + idx);
            }
        }

        #pragma unroll
        for (int l = 0; l < 2; ++l) {
            short8 xh[2], xl[2];
            #pragma unroll
            for (int kk = 0; kk < 2; ++kk) {
                const float* s = &tw[fr][kk * 32 + fq * 8];
                float4 a = *(const float4*)s;
                float4 b4 = *(const float4*)(s + 4);
                float v[8] = {a.x, a.y, a.z, a.w, b4.x, b4.y, b4.z, b4.w};
                #pragma unroll
                for (int j = 0; j < 8; ++j) {
                    unsigned short hh = f32_to_bf16_rne(v[j]);
                    xh[kk][j] = (short)hh;
                    xl[kk][j] = (short)f32_to_bf16_rne(v[j] - bf16_bits_to_f32(hh));
                }
            }
            f32x4 acc[4];
            #pragma unroll
            for (int nt = 0; nt < 4; ++nt) {
                float bb = bia[l][nt];
                acc[nt] = f32x4{bb, bb, bb, bb};
                #pragma unroll
                for (int kk = 0; kk < 2; ++kk) {
                    short8 w8 = *(const short8*)&wlds[l][nt * 16 + fr][kk * 32 + fq * 8];
                    if (!(IN_BF16 && l == 0))
                        acc[nt] = __builtin_amdgcn_mfma_f32_16x16x32_bf16(xl[kk], w8, acc[nt], 0, 0, 0);
                    acc[nt] = __builtin_amdgcn_mfma_f32_16x16x32_bf16(xh[kk], w8, acc[nt], 0, 0, 0);
                }
            }
            #pragma unroll
            for (int nt = 0; nt < 4; ++nt)
                #pragma unroll
                for (int j = 0; j < 4; ++j) {
                    float* cell = &tw[fq * 4 + j][nt * 16 + fr];
                    *cell = fmaxf(acc[nt][j], 0.f) + *cell;
                }
        }

        float y2[4][4], sm[4], sq[4];
        #pragma unroll
        for (int j = 0; j < 4; ++j) { sm[j] = 0.f; sq[j] = 0.f; }
        #pragma unroll
        for (int nt = 0; nt < 4; ++nt)
            #pragma unroll
            for (int j = 0; j < 4; ++j) {
                float v = tw[fq * 4 + j][nt * 16 + fr];
                y2[nt][j] = v;
                sm[j] += v; sq[j] += v * v;
            }
        #pragma unroll
        for (int off = 1; off < 16; off <<= 1) {
            #pragma unroll
            for (int j = 0; j < 4; ++j) {
                sm[j] += __shfl_xor(sm[j], off);
                sq[j] += __shfl_xor(sq[j], off);
            }
        }
        #pragma unroll
        for (int j = 0; j < 4; ++j) {
            float mu  = sm[j] * (1.f / 64.f);
            float var = sq[j] * (1.f / 64.f) - mu * mu;
            float rs  = rsqrtf(var + 1e-5f);
            #pragma unroll
            for (int nt = 0; nt < 4; ++nt)
                tw[fq * 4 + j][nt * 16 + fr] = (y2[nt][j] - mu) * rs * gam[nt] + bet[nt];
        }

        #pragma unroll
        for (int it = 0; it < 4; ++it) {
            int idx = it * 256 + lane * 4;
            *(float4*)(baseo + idx) = *(const float4*)&tw[idx >> 6][idx & 63];
        }
    }
}

extern "C" void kernel_launch(void* const* d_in, const int* in_sizes, int n_in,
                              void* d_out, int out_size, void* d_ws, size_t ws_size,
                              hipStream_t stream) {
    const int*   rows  = (const int*)d_in[0];
    const int*   cols  = (const int*)d_in[1];
    const float* vals  = (const float*)d_in[2];
    const float* ini   = (const float*)d_in[3];
    const float* Ws    = (const float*)d_in[4];
    const float* bs    = (const float*)d_in[5];
    const float* gamma = (const float*)d_in[6];
    const float* beta  = (const float*)d_in[7];
    float* out = (float*)d_out;
    int E = in_sizes[0];

    size_t A_b   = (size_t)NN * 32 * 4;                           // bf16 rows buffer
    size_t e8    = (size_t)E * 8;
    size_t B_b   = (A_b > e8) ? A_b : e8;                         // packed1 / e1_bf union
    size_t C_b   = e8;                                            // packed2
    size_t run_b = (size_t)NBKT * MAXRUN * 8;
    size_t rcp_b = ((size_t)NBKT * CPAD * 4 + 63) & ~(size_t)63;
    size_t gc_b  = 64;
    size_t rp_b  = (((size_t)NN + 1) * 4 + 63) & ~(size_t)63;
    size_t bst_b = (((size_t)NBKT + 1) * 4 + 63) & ~(size_t)63;
    size_t need  = A_b + B_b + C_b + run_b + 2 * rcp_b + gc_b + rp_b + bst_b;

    int epb = (E + NCH - 1) / NCH;
    if (ws_size >= need && epb <= (RITER * 1024) && (size_t)E <= (size_t)NCH * EPB_CAP) {
        char* w = (char*)d_ws;
        unsigned* Abuf     = (unsigned*)w;  w += A_b;   // ini_bf -> hop2 out -> mlp in
        char*     Bbuf     = w;             w += B_b;   // packed1, then e1_bf
        int2*     packed2  = (int2*)w;      w += C_b;
        int2*     runlist  = (int2*)w;      w += run_b;
        int*      runcnt_p = (int*)w;       w += rcp_b;
        int*      tot_p    = (int*)w;       w += rcp_b;
        int*      gcur     = (int*)w;       w += gc_b;  // zeroed with the counters
        int*      rp       = (int*)w;       w += rp_b;
        int*      bktstart = (int*)w;

        int2*     packed1  = (int2*)Bbuf;
        unsigned* e1_bf    = (unsigned*)Bbuf;

        cvt_bf16<<<2048, 256, 0, stream>>>((const float2*)ini, Abuf, NN * 32);
        int zn = (int)((2 * rcp_b + gc_b) / 4);
        zero_i<<<(zn + 255) / 256, 256, 0, stream>>>(runcnt_p, zn);
        scatter_v4<<<NCH, 1024, 0, stream>>>(rows, cols, vals, gcur, runcnt_p,
                                             runlist, tot_p, packed1, E, epb);
        bkt_scan3<<<1, 1024, 0, stream>>>(tot_p, bktstart, rp, E);
        sort_v3<<<NBKT, 1024, 0, stream>>>(bktstart, runcnt_p, runlist,
                                           packed1, packed2, rp);
        spmm_g<<<NTILE, 256, 0, stream>>>(rp, rp + 1, packed2, (const uint2*)Abuf,
                                          (uint2*)e1_bf, NN);
        spmm_g<<<NTILE, 256, 0, stream>>>(rp, rp + 1, packed2, (const uint2*)e1_bf,
                                          (uint2*)Abuf, NN);
        mlp_v2<1><<<1024, 256, 0, stream>>>((const uint2*)Abuf, out, Ws, bs, gamma, beta);
    } else {
        float* e1 = (float*)d_ws;
        int n4 = out_size / 4;
        int zb = (n4 + 255) / 256;
        zero_f4<<<zb, 256, 0, stream>>>((float4*)e1,  n4);
        zero_f4<<<zb, 256, 0, stream>>>((float4*)out, n4);
        spmm_scatter<<<12800, 256, 0, stream>>>(rows, cols, vals, ini, e1, E);
        spmm_scatter<<<12800, 256, 0, stream>>>(rows, cols, vals, e1, out, E);
        mlp_v2<0><<<1024, 256, 0, stream>>>(nullptr, out, Ws, bs, gamma, beta);
    }
}